// Round 1
// baseline (10198.997 us; speedup 1.0000x reference)
//
#include <hip/hip_runtime.h>
#include <hip/hip_bf16.h>

#define B_ 4
#define S_ 1024
#define E_ 1024
#define A_ 64
#define H_ 16
#define L_ 2

static constexpr float LN_EPS = 1e-5f;
static constexpr float INV_SCALE = 1.0f / 32.0f;  // 1/sqrt(E), E=1024

// ---------------- block reductions (256 threads = 4 waves) ----------------
__device__ __forceinline__ float block_sum256(float v, float* red) {
#pragma unroll
  for (int o = 32; o > 0; o >>= 1) v += __shfl_down(v, o, 64);
  const int lane = threadIdx.x & 63;
  const int w = threadIdx.x >> 6;
  if (lane == 0) red[w] = v;
  __syncthreads();
  if (threadIdx.x == 0) red[0] = red[0] + red[1] + red[2] + red[3];
  __syncthreads();
  float r = red[0];
  __syncthreads();
  return r;
}

__device__ __forceinline__ float block_max256(float v, float* red) {
#pragma unroll
  for (int o = 32; o > 0; o >>= 1) v = fmaxf(v, __shfl_down(v, o, 64));
  const int lane = threadIdx.x & 63;
  const int w = threadIdx.x >> 6;
  if (lane == 0) red[w] = v;
  __syncthreads();
  if (threadIdx.x == 0) red[0] = fmaxf(fmaxf(red[0], red[1]), fmaxf(red[2], red[3]));
  __syncthreads();
  float r = red[0];
  __syncthreads();
  return r;
}

// ---------------- embedding gather + LayerNorm (layer 0) ----------------
// one block per (b,s) row; heads are broadcast at layer 0 so we LN once per row
__global__ __launch_bounds__(256) void embed_ln_kernel(
    const int* __restrict__ x, const float* __restrict__ emb,
    const float* __restrict__ gamma, const float* __restrict__ beta,
    float* __restrict__ out) {
  __shared__ float red[4];
  const int row = blockIdx.x;  // b*S + s
  const int tid = threadIdx.x;
  const float* src = emb + (long)x[row] * E_;
  float vals[4];
  float s = 0.f;
#pragma unroll
  for (int i = 0; i < 4; ++i) { vals[i] = src[tid + 256 * i]; s += vals[i]; }
  const float mean = block_sum256(s, red) * (1.f / E_);
  float sq = 0.f;
#pragma unroll
  for (int i = 0; i < 4; ++i) { float d = vals[i] - mean; sq += d * d; }
  const float var = block_sum256(sq, red) * (1.f / E_);
  const float rstd = rsqrtf(var + LN_EPS);
  float* dst = out + (long)row * E_;
#pragma unroll
  for (int i = 0; i < 4; ++i) {
    const int e = tid + 256 * i;
    dst[e] = (vals[i] - mean) * rstd * gamma[e] + beta[e];
  }
}

// ---------------- in-place LayerNorm (layer >= 1) ----------------
// one block per (b,h,s) row; no residual in this model so in-place is safe
__global__ __launch_bounds__(256) void ln_inplace_kernel(
    float* __restrict__ h, const float* __restrict__ gamma,
    const float* __restrict__ beta) {
  __shared__ float red[4];
  const long row = blockIdx.x;  // b*H*S + h*S + s
  const int tid = threadIdx.x;
  float* p = h + row * (long)E_;
  float vals[4];
  float s = 0.f;
#pragma unroll
  for (int i = 0; i < 4; ++i) { vals[i] = p[tid + 256 * i]; s += vals[i]; }
  const float mean = block_sum256(s, red) * (1.f / E_);
  float sq = 0.f;
#pragma unroll
  for (int i = 0; i < 4; ++i) { float d = vals[i] - mean; sq += d * d; }
  const float var = block_sum256(sq, red) * (1.f / E_);
  const float rstd = rsqrtf(var + LN_EPS);
#pragma unroll
  for (int i = 0; i < 4; ++i) {
    const int e = tid + 256 * i;
    p[e] = (vals[i] - mean) * rstd * gamma[e] + beta[e];
  }
}

// ---------------- row softmax over S, in place, with 1/sqrt(E) scale ----------------
__global__ __launch_bounds__(256) void softmax_kernel(float* __restrict__ sc) {
  __shared__ float red[4];
  const long row = blockIdx.x;  // b*H*S + h*S + s
  float* p = sc + row * (long)S_;
  const int tid = threadIdx.x;
  float v[4];
  float m = -1e30f;
#pragma unroll
  for (int i = 0; i < 4; ++i) { v[i] = p[tid + 256 * i] * INV_SCALE; m = fmaxf(m, v[i]); }
  m = block_max256(m, red);
  float s = 0.f;
#pragma unroll
  for (int i = 0; i < 4; ++i) { v[i] = __expf(v[i] - m); s += v[i]; }
  s = block_sum256(s, red);
  const float inv = 1.f / s;
#pragma unroll
  for (int i = 0; i < 4; ++i) p[tid + 256 * i] = v[i] * inv;
}

// ---------------- batched tiled f32 GEMM ----------------
// C[batch] = A[batch] (MxK, row-major) * op(B[batch]),
// op(B) = B^T if TRANS_B (B is [N,K] row-major) else B ([K,N] row-major).
// batch = b*H + h; A offset = b*aStrideB + h*aStrideH; B offset = b*bStrideB + h*bStrideH;
// C is contiguous [batch][M][N].
template <int BM, int BN, int BK, int TM, int TN, bool TRANS_B>
__global__ __launch_bounds__(256) void gemm_f32(
    const float* __restrict__ Aall, const float* __restrict__ Ball,
    float* __restrict__ Call, int M, int N, int K,
    long aStrideB, long aStrideH, long bStrideB, long bStrideH, int Hn) {
  const int batch = blockIdx.z;
  const int bb = batch / Hn, hh = batch % Hn;
  const float* Ap = Aall + (long)bb * aStrideB + (long)hh * aStrideH;
  const float* Bp = Ball + (long)bb * bStrideB + (long)hh * bStrideH;
  float* C = Call + (long)batch * M * N;

  __shared__ float As[BK][BM + 4];  // +4 keeps rows 16B-aligned, breaks some conflicts
  __shared__ float Bs[BK][BN + 4];

  const int tid = threadIdx.x;
  const int bm = blockIdx.x * BM;
  const int bn = blockIdx.y * BN;
  const int tx = tid % (BN / TN);
  const int ty = tid / (BN / TN);

  float acc[TM][TN];
#pragma unroll
  for (int i = 0; i < TM; ++i)
#pragma unroll
    for (int j = 0; j < TN; ++j) acc[i][j] = 0.f;

  for (int k0 = 0; k0 < K; k0 += BK) {
    // A tile: [BM][BK] -> As[k][m] (coalesced along K)
#pragma unroll
    for (int idx = tid; idx < BM * BK; idx += 256) {
      const int r = idx / BK, c = idx % BK;
      As[c][r] = Ap[(long)(bm + r) * K + (k0 + c)];
    }
    if (TRANS_B) {
      // B is [N,K]: Bs[k][n] = B[bn+n][k0+c]
#pragma unroll
      for (int idx = tid; idx < BN * BK; idx += 256) {
        const int n = idx / BK, c = idx % BK;
        Bs[c][n] = Bp[(long)(bn + n) * K + (k0 + c)];
      }
    } else {
      // B is [K,N]: Bs[k][n] = B[k0+c][bn+n] (coalesced along N)
#pragma unroll
      for (int idx = tid; idx < BN * BK; idx += 256) {
        const int n = idx % BN, c = idx / BN;
        Bs[c][n] = Bp[(long)(k0 + c) * N + (bn + n)];
      }
    }
    __syncthreads();
#pragma unroll
    for (int kk = 0; kk < BK; ++kk) {
      float a[TM], bv[TN];
#pragma unroll
      for (int i = 0; i < TM; ++i) a[i] = As[kk][ty * TM + i];
#pragma unroll
      for (int j = 0; j < TN; ++j) bv[j] = Bs[kk][tx * TN + j];
#pragma unroll
      for (int i = 0; i < TM; ++i)
#pragma unroll
        for (int j = 0; j < TN; ++j) acc[i][j] = fmaf(a[i], bv[j], acc[i][j]);
    }
    __syncthreads();
  }
#pragma unroll
  for (int i = 0; i < TM; ++i) {
    const long crow = (long)(bm + ty * TM + i) * N + bn + tx * TN;
#pragma unroll
    for (int j = 0; j < TN; ++j) C[crow + j] = acc[i][j];
  }
}

// ---------------- launch ----------------
extern "C" void kernel_launch(void* const* d_in, const int* in_sizes, int n_in,
                              void* d_out, int out_size, void* d_ws, size_t ws_size,
                              hipStream_t stream) {
  const int* x = (const int*)d_in[0];
  const float* emb = (const float*)d_in[1];
  const float* gamma = (const float*)d_in[2];  // [L,E]
  const float* beta = (const float*)d_in[3];   // [L,E]
  const float* Wq = (const float*)d_in[4];     // [L,H,A,E]
  const float* Wk = (const float*)d_in[5];     // [L,H,A,E]
  const float* Wv = (const float*)d_in[6];     // [L,H,E,E]
  float* out = (float*)d_out;                  // [B,H,S,E] f32

  // workspace layout (f32): hn0 | q | k | v | scores  (~560 MB)
  float* hn0 = (float*)d_ws;                                  // B*S*E
  float* q = hn0 + (size_t)B_ * S_ * E_;                      // B*H*S*A
  float* k = q + (size_t)B_ * H_ * S_ * A_;                   // B*H*S*A
  float* v = k + (size_t)B_ * H_ * S_ * A_;                   // B*H*S*E
  float* sc = v + (size_t)B_ * H_ * S_ * E_;                  // B*H*S*S

  const dim3 blk(256);
  const dim3 grid_qk(S_ / 128, A_ / 64, B_ * H_);
  const dim3 grid_big(S_ / 128, E_ / 128, B_ * H_);

  for (int l = 0; l < L_; ++l) {
    const float* hin;
    long aSB, aSH;
    if (l == 0) {
      embed_ln_kernel<<<B_ * S_, blk, 0, stream>>>(x, emb, gamma, beta, hn0);
      hin = hn0; aSB = (long)S_ * E_; aSH = 0;  // heads broadcast at layer 0
    } else {
      ln_inplace_kernel<<<B_ * H_ * S_, blk, 0, stream>>>(
          out, gamma + (long)l * E_, beta + (long)l * E_);
      hin = out; aSB = (long)H_ * S_ * E_; aSH = (long)S_ * E_;
    }
    // Q = hn * Wq[l,h]^T   [S,A]
    gemm_f32<128, 64, 16, 8, 4, true><<<grid_qk, blk, 0, stream>>>(
        hin, Wq + (long)l * H_ * A_ * E_, q, S_, A_, E_,
        aSB, aSH, 0L, (long)A_ * E_, H_);
    // K = hn * Wk[l,h]^T   [S,A]
    gemm_f32<128, 64, 16, 8, 4, true><<<grid_qk, blk, 0, stream>>>(
        hin, Wk + (long)l * H_ * A_ * E_, k, S_, A_, E_,
        aSB, aSH, 0L, (long)A_ * E_, H_);
    // V = hn * Wv[l,h]^T   [S,E]
    gemm_f32<128, 128, 16, 8, 8, true><<<grid_big, blk, 0, stream>>>(
        hin, Wv + (long)l * H_ * E_ * E_, v, S_, E_, E_,
        aSB, aSH, 0L, (long)E_ * E_, H_);
    // scores = Q * K^T     [S,S], K(contraction)=A=64
    gemm_f32<128, 128, 16, 8, 8, true><<<grid_big, blk, 0, stream>>>(
        q, k, sc, S_, S_, A_,
        (long)H_ * S_ * A_, (long)S_ * A_, (long)H_ * S_ * A_, (long)S_ * A_, H_);
    // softmax rows (with 1/sqrt(E) scale)
    softmax_kernel<<<B_ * H_ * S_, blk, 0, stream>>>(sc);
    // out = softmax(scores) * V   [S,E]; writes d_out (layer0 hidden lives in d_out)
    gemm_f32<128, 128, 16, 8, 8, false><<<grid_big, blk, 0, stream>>>(
        sc, v, out, S_, E_, S_,
        (long)H_ * S_ * S_, (long)S_ * S_, (long)H_ * S_ * E_, (long)S_ * E_, H_);
  }
}

// Round 2
// 1193.849 us; speedup vs baseline: 8.5430x; 8.5430x over previous
//
#include <hip/hip_runtime.h>

#define B_ 4
#define S_ 1024
#define E_ 1024
#define A_ 64
#define H_ 16
#define L_ 2

static constexpr float LN_EPS = 1e-5f;
static constexpr float INV_SCALE = 1.0f / 32.0f;  // 1/sqrt(E), E=1024

typedef __attribute__((ext_vector_type(8))) short bf16x8;  // 8 bf16 = 4 VGPRs
typedef __attribute__((ext_vector_type(4))) float f32x4;

// ---------------- bf16 helpers (RNE, header-version independent) ----------------
__device__ __forceinline__ unsigned short f2bf(float f) {
  unsigned u = __float_as_uint(f);
  u += 0x7fffu + ((u >> 16) & 1u);
  return (unsigned short)(u >> 16);
}
__device__ __forceinline__ float bf2f(unsigned short s) {
  return __uint_as_float(((unsigned)s) << 16);
}

// ---------------- block reductions (256 threads = 4 waves) ----------------
__device__ __forceinline__ float block_sum256(float v, float* red) {
#pragma unroll
  for (int o = 32; o > 0; o >>= 1) v += __shfl_down(v, o, 64);
  const int lane = threadIdx.x & 63;
  const int w = threadIdx.x >> 6;
  if (lane == 0) red[w] = v;
  __syncthreads();
  if (threadIdx.x == 0) red[0] = red[0] + red[1] + red[2] + red[3];
  __syncthreads();
  float r = red[0];
  __syncthreads();
  return r;
}

__device__ __forceinline__ float block_max256(float v, float* red) {
#pragma unroll
  for (int o = 32; o > 0; o >>= 1) v = fmaxf(v, __shfl_down(v, o, 64));
  const int lane = threadIdx.x & 63;
  const int w = threadIdx.x >> 6;
  if (lane == 0) red[w] = v;
  __syncthreads();
  if (threadIdx.x == 0) red[0] = fmaxf(fmaxf(red[0], red[1]), fmaxf(red[2], red[3]));
  __syncthreads();
  float r = red[0];
  __syncthreads();
  return r;
}

// ---------------- f32 -> bf16 bulk convert (weights) ----------------
__global__ __launch_bounds__(256) void cvt_f32_bf16(const float* __restrict__ in,
                                                    unsigned short* __restrict__ out, long n) {
  long i = ((long)blockIdx.x * 256 + threadIdx.x) * 4;
  const long stride = (long)gridDim.x * 1024;
  for (; i < n; i += stride) {
    float4 v = *(const float4*)(in + i);
    ushort4 o;
    o.x = f2bf(v.x); o.y = f2bf(v.y); o.z = f2bf(v.z); o.w = f2bf(v.w);
    *(ushort4*)(out + i) = o;
  }
}

// ---------------- embedding gather + LayerNorm -> bf16 (layer 0) ----------------
__global__ __launch_bounds__(256) void embed_ln_kernel(
    const int* __restrict__ x, const float* __restrict__ emb,
    const float* __restrict__ gamma, const float* __restrict__ beta,
    unsigned short* __restrict__ out) {
  __shared__ float red[4];
  const int row = blockIdx.x;  // b*S + s
  const int tid = threadIdx.x;
  const float* src = emb + (long)x[row] * E_;
  float4 v = *(const float4*)(src + tid * 4);
  const float mean = block_sum256(v.x + v.y + v.z + v.w, red) * (1.f / E_);
  float dx = v.x - mean, dy = v.y - mean, dz = v.z - mean, dw = v.w - mean;
  const float var = block_sum256(dx * dx + dy * dy + dz * dz + dw * dw, red) * (1.f / E_);
  const float rstd = rsqrtf(var + LN_EPS);
  float4 g = *(const float4*)(gamma + tid * 4);
  float4 b = *(const float4*)(beta + tid * 4);
  ushort4 o;
  o.x = f2bf(dx * rstd * g.x + b.x);
  o.y = f2bf(dy * rstd * g.y + b.y);
  o.z = f2bf(dz * rstd * g.z + b.z);
  o.w = f2bf(dw * rstd * g.w + b.w);
  *(ushort4*)(out + (long)row * E_ + tid * 4) = o;
}

// ---------------- LayerNorm f32 -> bf16 (layer >= 1) ----------------
__global__ __launch_bounds__(256) void ln_f32_bf16_kernel(
    const float* __restrict__ h, const float* __restrict__ gamma,
    const float* __restrict__ beta, unsigned short* __restrict__ out) {
  __shared__ float red[4];
  const long row = blockIdx.x;  // b*H*S + h*S + s
  const int tid = threadIdx.x;
  float4 v = *(const float4*)(h + row * (long)E_ + tid * 4);
  const float mean = block_sum256(v.x + v.y + v.z + v.w, red) * (1.f / E_);
  float dx = v.x - mean, dy = v.y - mean, dz = v.z - mean, dw = v.w - mean;
  const float var = block_sum256(dx * dx + dy * dy + dz * dz + dw * dw, red) * (1.f / E_);
  const float rstd = rsqrtf(var + LN_EPS);
  float4 g = *(const float4*)(gamma + tid * 4);
  float4 b = *(const float4*)(beta + tid * 4);
  ushort4 o;
  o.x = f2bf(dx * rstd * g.x + b.x);
  o.y = f2bf(dy * rstd * g.y + b.y);
  o.z = f2bf(dz * rstd * g.z + b.z);
  o.w = f2bf(dw * rstd * g.w + b.w);
  *(ushort4*)(out + row * E_ + tid * 4) = o;
}

// ---------------- softmax over S, bf16 in-place (scores already scaled) ----------------
__global__ __launch_bounds__(256) void softmax_bf16_kernel(unsigned short* __restrict__ sc) {
  __shared__ float red[4];
  unsigned short* p = sc + (long)blockIdx.x * S_;
  const int tid = threadIdx.x;
  ushort4 raw = *(const ushort4*)(p + tid * 4);
  float v0 = bf2f(raw.x), v1 = bf2f(raw.y), v2 = bf2f(raw.z), v3 = bf2f(raw.w);
  float m = block_max256(fmaxf(fmaxf(v0, v1), fmaxf(v2, v3)), red);
  v0 = __expf(v0 - m); v1 = __expf(v1 - m); v2 = __expf(v2 - m); v3 = __expf(v3 - m);
  const float s = block_sum256(v0 + v1 + v2 + v3, red);
  const float inv = 1.f / s;
  ushort4 o;
  o.x = f2bf(v0 * inv); o.y = f2bf(v1 * inv); o.z = f2bf(v2 * inv); o.w = f2bf(v3 * inv);
  *(ushort4*)(p + tid * 4) = o;  // each thread rewrites only its own elements: race-free
}

// ---------------- global -> LDS direct load (16B/lane) ----------------
__device__ __forceinline__ void gload_lds16(const void* g, void* l) {
  __builtin_amdgcn_global_load_lds((const __attribute__((address_space(1))) void*)g,
                                   (__attribute__((address_space(3))) void*)l, 16, 0, 0);
}

// Stage a [ROWS][64] bf16 tile into LDS, linear dest, with the XOR-(row&7)
// swizzle realized by inverse-swizzling the per-lane GLOBAL source (G21 rule).
// LDS linear slot s of row r holds global k-slot (s ^ (r&7)). 16B slots.
template <int ROWS>
__device__ __forceinline__ void stage_tile(const unsigned short* __restrict__ src, int ldK,
                                           unsigned short* lds, int tid) {
  const int rb = tid >> 3;                    // 0..31 (row within 32-row chunk)
  const int gslot = (tid & 7) ^ (rb & 7);     // inverse swizzle on the source
  const int wbase = (tid >> 6) * 512;         // wave-uniform LDS base (shorts)
#pragma unroll
  for (int i = 0; i < ROWS / 32; ++i) {
    const unsigned short* g = src + (long)(i * 32 + rb) * ldK + gslot * 8;
    gload_lds16(g, lds + i * 2048 + wbase);
  }
}

// Read one 16B bf16 fragment (8 elems along K) at (row r, k-slot) with swizzled addr.
__device__ __forceinline__ bf16x8 lds_frag(const unsigned short* base, int r, int slot) {
  const int byteoff = (r << 7) + ((slot ^ (r & 7)) << 4);
  return *(const bf16x8*)((const char*)base + byteoff);
}

// ---------------- batched bf16 MFMA GEMM, NT: C = A[M,K] * B[N,K]^T ----------------
// batch = b*Hn + h; operand offsets via (aSB,aSH)/(bSB,bSH); C contiguous [batch][M][N].
// 256 threads = 4 waves in 2x2; wave tile (BM/2)x(BN/2); 16x16x32 bf16 MFMA, BK=64.
template <int BM, int BN, bool OUT_BF16>
__global__ __launch_bounds__(256) void mfma_gemm_nt(
    const unsigned short* __restrict__ Aall, const unsigned short* __restrict__ Ball,
    void* __restrict__ Call, int M, int N, int K,
    long aSB, long aSH, long bSB, long bSH, int Hn, float alpha) {
  __shared__ unsigned short As[BM * 64];
  __shared__ unsigned short Bs[BN * 64];
  const int batch = blockIdx.z;
  const int bb = batch / Hn, hh = batch % Hn;
  const unsigned short* Ap = Aall + (long)bb * aSB + (long)hh * aSH;
  const unsigned short* Bp = Ball + (long)bb * bSB + (long)hh * bSH;
  const int tid = threadIdx.x;
  const int lane = tid & 63;
  const int wave = tid >> 6;
  const int wr = wave >> 1, wc = wave & 1;
  const int bm = blockIdx.x * BM, bn = blockIdx.y * BN;
  constexpr int FM = BM / 32, FN = BN / 32;

  f32x4 acc[FM][FN];
#pragma unroll
  for (int i = 0; i < FM; ++i)
#pragma unroll
    for (int j = 0; j < FN; ++j) acc[i][j] = (f32x4)(0.f);

  for (int k0 = 0; k0 < K; k0 += 64) {
    stage_tile<BM>(Ap + (long)bm * K + k0, K, As, tid);
    stage_tile<BN>(Bp + (long)bn * K + k0, K, Bs, tid);
    __syncthreads();  // compiler drains vmcnt before s_barrier
#pragma unroll
    for (int kb = 0; kb < 2; ++kb) {
      const int slot = (kb << 2) + (lane >> 4);
      bf16x8 af[FM], bfv[FN];
#pragma unroll
      for (int mi = 0; mi < FM; ++mi)
        af[mi] = lds_frag(As, wr * (BM / 2) + mi * 16 + (lane & 15), slot);
#pragma unroll
      for (int ni = 0; ni < FN; ++ni)
        bfv[ni] = lds_frag(Bs, wc * (BN / 2) + ni * 16 + (lane & 15), slot);
#pragma unroll
      for (int mi = 0; mi < FM; ++mi)
#pragma unroll
        for (int ni = 0; ni < FN; ++ni)
          acc[mi][ni] = __builtin_amdgcn_mfma_f32_16x16x32_bf16(af[mi], bfv[ni], acc[mi][ni], 0, 0, 0);
    }
    __syncthreads();
  }

  // epilogue: C/D layout col=lane&15, row=(lane>>4)*4+reg  [verified m89/m91]
#pragma unroll
  for (int mi = 0; mi < FM; ++mi) {
    const int row = bm + wr * (BM / 2) + mi * 16 + ((lane >> 4) << 2);
#pragma unroll
    for (int ni = 0; ni < FN; ++ni) {
      const int col = bn + wc * (BN / 2) + ni * 16 + (lane & 15);
#pragma unroll
      for (int r = 0; r < 4; ++r) {
        const float v = acc[mi][ni][r] * alpha;
        const long idx = (long)batch * M * N + (long)(row + r) * N + col;
        if constexpr (OUT_BF16)
          ((unsigned short*)Call)[idx] = f2bf(v);
        else
          ((float*)Call)[idx] = v;
      }
    }
  }
}

// ---------------- launch ----------------
extern "C" void kernel_launch(void* const* d_in, const int* in_sizes, int n_in,
                              void* d_out, int out_size, void* d_ws, size_t ws_size,
                              hipStream_t stream) {
  const int* x = (const int*)d_in[0];
  const float* emb = (const float*)d_in[1];
  const float* gamma = (const float*)d_in[2];  // [L,E]
  const float* beta = (const float*)d_in[3];   // [L,E]
  const float* Wq = (const float*)d_in[4];     // [L,H,A,E]
  const float* Wk = (const float*)d_in[5];     // [L,H,A,E]
  const float* Wv = (const float*)d_in[6];     // [L,H,E,E]
  float* out = (float*)d_out;                  // [B,H,S,E] f32

  // workspace (bf16 shorts): wq | wk | wv | hn | q | k | v_t | sc   (~495 MB)
  const long WQK_N = (long)L_ * H_ * A_ * E_;      // 2M
  const long WV_N = (long)L_ * H_ * E_ * E_;       // 32M
  const long HN_N = (long)B_ * H_ * S_ * E_;       // 64M
  const long QK_N = (long)B_ * H_ * S_ * A_;       // 4M
  unsigned short* wq_bf = (unsigned short*)d_ws;
  unsigned short* wk_bf = wq_bf + WQK_N;
  unsigned short* wv_bf = wk_bf + WQK_N;
  unsigned short* hn = wv_bf + WV_N;               // [B,(H),S,E] bf16
  unsigned short* q = hn + HN_N;                   // [B,H,S,A]
  unsigned short* k = q + QK_N;                    // [B,H,S,A]
  unsigned short* v_t = k + QK_N;                  // [B,H,E,S]  (V transposed)
  unsigned short* sc = v_t + HN_N;                 // [B,H,S,S]

  const dim3 blk(256);
  cvt_f32_bf16<<<512, blk, 0, stream>>>(Wq, wq_bf, WQK_N);
  cvt_f32_bf16<<<512, blk, 0, stream>>>(Wk, wk_bf, WQK_N);
  cvt_f32_bf16<<<2048, blk, 0, stream>>>(Wv, wv_bf, WV_N);

  for (int l = 0; l < L_; ++l) {
    long hSB, hSH;  // hn batch strides (A or B operand)
    if (l == 0) {
      embed_ln_kernel<<<B_ * S_, blk, 0, stream>>>(x, emb, gamma, beta, hn);
      hSB = (long)S_ * E_; hSH = 0;  // heads broadcast at layer 0
    } else {
      ln_f32_bf16_kernel<<<B_ * H_ * S_, blk, 0, stream>>>(
          out, gamma + (long)l * E_, beta + (long)l * E_, hn);
      hSB = (long)H_ * S_ * E_; hSH = (long)S_ * E_;
    }
    // q = hn * Wq[l,h]^T  [S,A] bf16
    mfma_gemm_nt<128, 64, true><<<dim3(8, 1, 64), blk, 0, stream>>>(
        hn, wq_bf + l * H_ * A_ * E_, q, S_, A_, E_,
        hSB, hSH, 0L, (long)A_ * E_, H_, 1.f);
    // k = hn * Wk[l,h]^T  [S,A] bf16
    mfma_gemm_nt<128, 64, true><<<dim3(8, 1, 64), blk, 0, stream>>>(
        hn, wk_bf + l * H_ * A_ * E_, k, S_, A_, E_,
        hSB, hSH, 0L, (long)A_ * E_, H_, 1.f);
    // v_t = Wv[l,h] * hn^T  [E,S] bf16  (V transposed, keeps PV as NT)
    mfma_gemm_nt<128, 128, true><<<dim3(8, 8, 64), blk, 0, stream>>>(
        wv_bf + (long)l * H_ * E_ * E_, hn, v_t, E_, S_, E_,
        0L, (long)E_ * E_, hSB, hSH, H_, 1.f);
    // sc = (q * k^T) / sqrt(E)  [S,S] bf16
    mfma_gemm_nt<128, 128, true><<<dim3(8, 8, 64), blk, 0, stream>>>(
        q, k, sc, S_, S_, A_,
        (long)H_ * S_ * A_, (long)S_ * A_, (long)H_ * S_ * A_, (long)S_ * A_, H_, INV_SCALE);
    // softmax rows, in place
    softmax_bf16_kernel<<<B_ * H_ * S_, blk, 0, stream>>>(sc);
    // out = probs * v_t^T  [S,E] f32 -> d_out (layer hidden lives in d_out)
    mfma_gemm_nt<128, 128, false><<<dim3(8, 8, 64), blk, 0, stream>>>(
        sc, v_t, out, S_, E_, S_,
        (long)H_ * S_ * S_, (long)S_ * S_, (long)H_ * E_ * S_, (long)E_ * S_, H_, 1.f);
  }
}

// Round 3
// 1016.714 us; speedup vs baseline: 10.0313x; 1.1742x over previous
//
#include <hip/hip_runtime.h>

#define B_ 4
#define S_ 1024
#define E_ 1024
#define A_ 64
#define H_ 16
#define L_ 2

static constexpr float LN_EPS = 1e-5f;
static constexpr float INV_SCALE = 1.0f / 32.0f;  // 1/sqrt(E), E=1024

typedef __attribute__((ext_vector_type(8))) short bf16x8;  // 8 bf16 = 4 VGPRs
typedef __attribute__((ext_vector_type(4))) float f32x4;

// ---------------- bf16 helpers (RNE) ----------------
__device__ __forceinline__ unsigned short f2bf(float f) {
  unsigned u = __float_as_uint(f);
  u += 0x7fffu + ((u >> 16) & 1u);
  return (unsigned short)(u >> 16);
}
__device__ __forceinline__ float bf2f(unsigned short s) {
  return __uint_as_float(((unsigned)s) << 16);
}

// ---------------- block reductions (256 threads = 4 waves) ----------------
__device__ __forceinline__ float block_sum256(float v, float* red) {
#pragma unroll
  for (int o = 32; o > 0; o >>= 1) v += __shfl_down(v, o, 64);
  const int lane = threadIdx.x & 63;
  const int w = threadIdx.x >> 6;
  if (lane == 0) red[w] = v;
  __syncthreads();
  if (threadIdx.x == 0) red[0] = red[0] + red[1] + red[2] + red[3];
  __syncthreads();
  float r = red[0];
  __syncthreads();
  return r;
}

__device__ __forceinline__ float block_max256(float v, float* red) {
#pragma unroll
  for (int o = 32; o > 0; o >>= 1) v = fmaxf(v, __shfl_down(v, o, 64));
  const int lane = threadIdx.x & 63;
  const int w = threadIdx.x >> 6;
  if (lane == 0) red[w] = v;
  __syncthreads();
  if (threadIdx.x == 0) red[0] = fmaxf(fmaxf(red[0], red[1]), fmaxf(red[2], red[3]));
  __syncthreads();
  float r = red[0];
  __syncthreads();
  return r;
}

// ---------------- weight converts ----------------
__global__ __launch_bounds__(256) void cvt_f32_bf16(const float* __restrict__ in,
                                                    unsigned short* __restrict__ out, long n) {
  long i = ((long)blockIdx.x * 256 + threadIdx.x) * 4;
  const long stride = (long)gridDim.x * 1024;
  for (; i < n; i += stride) {
    float4 v = *(const float4*)(in + i);
    ushort4 o;
    o.x = f2bf(v.x); o.y = f2bf(v.y); o.z = f2bf(v.z); o.w = f2bf(v.w);
    *(ushort4*)(out + i) = o;
  }
}

// concat Wq/Wk -> wqk[l,h,128,E] bf16 (rows 0-63 = Wq, 64-127 = Wk)
__global__ __launch_bounds__(256) void cvt_qk_concat(const float* __restrict__ Wq,
                                                     const float* __restrict__ Wk,
                                                     unsigned short* __restrict__ out) {
  const long total = (long)L_ * H_ * 128 * E_;
  long i = ((long)blockIdx.x * 256 + threadIdx.x) * 4;
  const long stride = (long)gridDim.x * 1024;
  for (; i < total; i += stride) {
    const long e = i % E_;
    const long rowhe = i / E_;
    const int row = (int)(rowhe % 128);
    const long lh = rowhe / 128;
    const float* src = (row < 64 ? Wq : Wk) + (lh * 64 + (row & 63)) * E_ + e;
    float4 v = *(const float4*)src;
    ushort4 o;
    o.x = f2bf(v.x); o.y = f2bf(v.y); o.z = f2bf(v.z); o.w = f2bf(v.w);
    *(ushort4*)(out + i) = o;
  }
}

// ---------------- embedding gather + LayerNorm -> bf16 (layer 0) ----------------
__global__ __launch_bounds__(256) void embed_ln_kernel(
    const int* __restrict__ x, const float* __restrict__ emb,
    const float* __restrict__ gamma, const float* __restrict__ beta,
    unsigned short* __restrict__ out) {
  __shared__ float red[4];
  const int row = blockIdx.x;  // b*S + s
  const int tid = threadIdx.x;
  const float* src = emb + (long)x[row] * E_;
  float4 v = *(const float4*)(src + tid * 4);
  const float mean = block_sum256(v.x + v.y + v.z + v.w, red) * (1.f / E_);
  float dx = v.x - mean, dy = v.y - mean, dz = v.z - mean, dw = v.w - mean;
  const float var = block_sum256(dx * dx + dy * dy + dz * dz + dw * dw, red) * (1.f / E_);
  const float rstd = rsqrtf(var + LN_EPS);
  float4 g = *(const float4*)(gamma + tid * 4);
  float4 b = *(const float4*)(beta + tid * 4);
  ushort4 o;
  o.x = f2bf(dx * rstd * g.x + b.x);
  o.y = f2bf(dy * rstd * g.y + b.y);
  o.z = f2bf(dz * rstd * g.z + b.z);
  o.w = f2bf(dw * rstd * g.w + b.w);
  *(ushort4*)(out + (long)row * E_ + tid * 4) = o;
}

// ---------------- LayerNorm bf16 -> bf16 (layer >= 1; hidden lives in d_out as bf16) ----
__global__ __launch_bounds__(256) void ln_bf16_kernel(
    const unsigned short* __restrict__ h, const float* __restrict__ gamma,
    const float* __restrict__ beta, unsigned short* __restrict__ out) {
  __shared__ float red[4];
  const long row = blockIdx.x;  // b*H*S + h*S + s
  const int tid = threadIdx.x;
  ushort4 raw = *(const ushort4*)(h + row * (long)E_ + tid * 4);
  float vx = bf2f(raw.x), vy = bf2f(raw.y), vz = bf2f(raw.z), vw = bf2f(raw.w);
  const float mean = block_sum256(vx + vy + vz + vw, red) * (1.f / E_);
  float dx = vx - mean, dy = vy - mean, dz = vz - mean, dw = vw - mean;
  const float var = block_sum256(dx * dx + dy * dy + dz * dz + dw * dw, red) * (1.f / E_);
  const float rstd = rsqrtf(var + LN_EPS);
  float4 g = *(const float4*)(gamma + tid * 4);
  float4 b = *(const float4*)(beta + tid * 4);
  ushort4 o;
  o.x = f2bf(dx * rstd * g.x + b.x);
  o.y = f2bf(dy * rstd * g.y + b.y);
  o.z = f2bf(dz * rstd * g.z + b.z);
  o.w = f2bf(dw * rstd * g.w + b.w);
  *(ushort4*)(out + row * E_ + tid * 4) = o;
}

// ---------------- softmax over S, bf16 in-place ----------------
__global__ __launch_bounds__(256) void softmax_bf16_kernel(unsigned short* __restrict__ sc) {
  __shared__ float red[4];
  unsigned short* p = sc + (long)blockIdx.x * S_;
  const int tid = threadIdx.x;
  ushort4 raw = *(const ushort4*)(p + tid * 4);
  float v0 = bf2f(raw.x), v1 = bf2f(raw.y), v2 = bf2f(raw.z), v3 = bf2f(raw.w);
  float m = block_max256(fmaxf(fmaxf(v0, v1), fmaxf(v2, v3)), red);
  v0 = __expf(v0 - m); v1 = __expf(v1 - m); v2 = __expf(v2 - m); v3 = __expf(v3 - m);
  const float s = block_sum256(v0 + v1 + v2 + v3, red);
  const float inv = 1.f / s;
  ushort4 o;
  o.x = f2bf(v0 * inv); o.y = f2bf(v1 * inv); o.z = f2bf(v2 * inv); o.w = f2bf(v3 * inv);
  *(ushort4*)(p + tid * 4) = o;
}

// ---------------- global -> LDS direct load (16B/lane) ----------------
__device__ __forceinline__ void gload_lds16(const void* g, void* l) {
  __builtin_amdgcn_global_load_lds((const __attribute__((address_space(1))) void*)g,
                                   (__attribute__((address_space(3))) void*)l, 16, 0, 0);
}

// ============================================================================
// 128x128 2-barrier kernel (proven round 1) — used for qk-proj and scores
// ============================================================================
template <int ROWS>
__device__ __forceinline__ void stage_tile(const unsigned short* __restrict__ src, int ldRow,
                                           unsigned short* lds, int tid) {
  const int rb = tid >> 3;                    // 0..31
  const int gslot = (tid & 7) ^ (rb & 7);     // inverse swizzle on the source
  const int wbase = (tid >> 6) * 512;         // wave-uniform LDS base (shorts)
#pragma unroll
  for (int i = 0; i < ROWS / 32; ++i) {
    const unsigned short* g = src + (long)(i * 32 + rb) * ldRow + gslot * 8;
    gload_lds16(g, lds + i * 2048 + wbase);
  }
}

__device__ __forceinline__ bf16x8 lds_frag(const unsigned short* base, int r, int slot) {
  const int byteoff = (r << 7) + ((slot ^ (r & 7)) << 4);
  return *(const bf16x8*)((const char*)base + byteoff);
}

template <int BM, int BN, bool OUT_BF16>
__global__ __launch_bounds__(256) void mfma_gemm_nt(
    const unsigned short* __restrict__ Aall, const unsigned short* __restrict__ Ball,
    void* __restrict__ Call, int M, int N, int K, int lda, int ldb,
    long aSB, long aSH, long bSB, long bSH, int Hn, float alpha) {
  __shared__ unsigned short As[BM * 64];
  __shared__ unsigned short Bs[BN * 64];
  const int batch = blockIdx.z;
  const int bb = batch / Hn, hh = batch % Hn;
  const unsigned short* Ap = Aall + (long)bb * aSB + (long)hh * aSH;
  const unsigned short* Bp = Ball + (long)bb * bSB + (long)hh * bSH;
  const int tid = threadIdx.x;
  const int lane = tid & 63;
  const int wave = tid >> 6;
  const int wr = wave >> 1, wc = wave & 1;
  const int bm = blockIdx.x * BM, bn = blockIdx.y * BN;
  constexpr int FM = BM / 32, FN = BN / 32;

  f32x4 acc[FM][FN];
#pragma unroll
  for (int i = 0; i < FM; ++i)
#pragma unroll
    for (int j = 0; j < FN; ++j) acc[i][j] = (f32x4)(0.f);

  for (int k0 = 0; k0 < K; k0 += 64) {
    stage_tile<BM>(Ap + (long)bm * lda + k0, lda, As, tid);
    stage_tile<BN>(Bp + (long)bn * ldb + k0, ldb, Bs, tid);
    __syncthreads();
#pragma unroll
    for (int kb = 0; kb < 2; ++kb) {
      const int slot = (kb << 2) + (lane >> 4);
      bf16x8 af[FM], bfv[FN];
#pragma unroll
      for (int mi = 0; mi < FM; ++mi)
        af[mi] = lds_frag(As, wr * (BM / 2) + mi * 16 + (lane & 15), slot);
#pragma unroll
      for (int ni = 0; ni < FN; ++ni)
        bfv[ni] = lds_frag(Bs, wc * (BN / 2) + ni * 16 + (lane & 15), slot);
#pragma unroll
      for (int mi = 0; mi < FM; ++mi)
#pragma unroll
        for (int ni = 0; ni < FN; ++ni)
          acc[mi][ni] = __builtin_amdgcn_mfma_f32_16x16x32_bf16(af[mi], bfv[ni], acc[mi][ni], 0, 0, 0);
    }
    __syncthreads();
  }

#pragma unroll
  for (int mi = 0; mi < FM; ++mi) {
    const int row = bm + wr * (BM / 2) + mi * 16 + ((lane >> 4) << 2);
#pragma unroll
    for (int ni = 0; ni < FN; ++ni) {
      const int col = bn + wc * (BN / 2) + ni * 16 + (lane & 15);
#pragma unroll
      for (int r = 0; r < 4; ++r) {
        const float v = acc[mi][ni][r] * alpha;
        const long idx = (long)batch * M * N + (long)(row + r) * N + col;
        if constexpr (OUT_BF16)
          ((unsigned short*)Call)[idx] = f2bf(v);
        else
          ((float*)Call)[idx] = v;
      }
    }
  }
}

// ============================================================================
// 256x256 8-wave deep-pipelined kernel (counted vmcnt) — for v_t and PV
// LDS: buf{0,1} x { A[2 khalf][256r x 32k], B[...] } = 2 x 64KB = 128KB dynamic.
// Per tile (BK=64): 2 phases (khalf). Per phase: 12 ds_read_b128, stage next
// tile's matching khalf (4 gload_lds), s_barrier, 32 MFMA, vmcnt(4)+s_barrier.
// vmcnt(4) leaves exactly this phase's 4 stage-loads outstanding -> the khalf
// needed by the NEXT phase (staged one full tile = 2 phases earlier) is landed
// for ALL waves (symmetric load streams + wait-before-barrier).
// ============================================================================
__device__ __forceinline__ void stage_unit256(const unsigned short* __restrict__ src, int ldRow,
                                              char* lds_unit, int tid) {
#pragma unroll
  for (int i = 0; i < 2; ++i) {
    const int r = i * 128 + (tid >> 2);
    const int sg = (tid & 3) ^ ((r >> 1) & 3);  // inverse swizzle on source
    const unsigned short* g = src + (long)r * ldRow + sg * 8;
    gload_lds16(g, lds_unit + i * 8192 + ((tid >> 6) << 10));
  }
}

__device__ __forceinline__ bf16x8 lds_frag256(const char* opbase, int kh, int r, int ss) {
  return *(const bf16x8*)(opbase + kh * 16384 + r * 64 + ((ss ^ ((r >> 1) & 3)) << 4));
}

template <bool OUT_BF16>
__global__ __launch_bounds__(512, 2) void mfma_gemm256_nt(
    const unsigned short* __restrict__ Aall, const unsigned short* __restrict__ Ball,
    void* __restrict__ Call, int M, int N, int K, int lda, int ldb,
    long aSB, long aSH, long bSB, long bSH, int Hn, float alpha) {
  extern __shared__ char lds[];
  // XCD-chunked bijective swizzle on the flat workgroup id (nwg % 8 == 0 here)
  const int nx = gridDim.x, ny = gridDim.y;
  const int nwg = nx * ny * gridDim.z;
  int f = blockIdx.x + nx * (blockIdx.y + ny * blockIdx.z);
  if ((nwg & 7) == 0) f = (f & 7) * (nwg >> 3) + (f >> 3);
  const int bx = f % nx;
  const int by = (f / nx) % ny;
  const int batch = f / (nx * ny);

  const int bb = batch / Hn, hh = batch % Hn;
  const unsigned short* Ap = Aall + (long)bb * aSB + (long)hh * aSH + (long)bx * 256 * lda;
  const unsigned short* Bp = Ball + (long)bb * bSB + (long)hh * bSH + (long)by * 256 * ldb;
  const int tid = threadIdx.x;
  const int lane = tid & 63;
  const int w = tid >> 6;
  const int wr = w >> 2, wc = w & 3;  // 2 (M) x 4 (N) waves; wave tile 128x64

  f32x4 acc[8][4];
#pragma unroll
  for (int i = 0; i < 8; ++i)
#pragma unroll
    for (int j = 0; j < 4; ++j) acc[i][j] = (f32x4)(0.f);

  const int NT = K >> 6;
  // prologue: tile 0 -> buf0 (A kh0, B kh0, A kh1, B kh1), then full drain
  stage_unit256(Ap, lda, lds, tid);
  stage_unit256(Bp, ldb, lds + 32768, tid);
  stage_unit256(Ap + 32, lda, lds + 16384, tid);
  stage_unit256(Bp + 32, ldb, lds + 32768 + 16384, tid);
  asm volatile("s_waitcnt vmcnt(0)\n\ts_barrier" ::: "memory");

  for (int t = 0; t < NT; ++t) {
    const char* cur = lds + (t & 1) * 65536;
    char* nxt = lds + ((t + 1) & 1) * 65536;
    const unsigned short* An = Ap + (long)(t + 1) * 64;
    const unsigned short* Bn = Bp + (long)(t + 1) * 64;
    const bool pf = (t + 1 < NT);
#pragma unroll
    for (int kh = 0; kh < 2; ++kh) {
      bf16x8 a[8], b[4];
      const int ss = lane >> 4;
#pragma unroll
      for (int mi = 0; mi < 8; ++mi)
        a[mi] = lds_frag256(cur, kh, wr * 128 + mi * 16 + (lane & 15), ss);
#pragma unroll
      for (int ni = 0; ni < 4; ++ni)
        b[ni] = lds_frag256(cur + 32768, kh, wc * 64 + ni * 16 + (lane & 15), ss);
      if (pf) {
        stage_unit256(An + kh * 32, lda, nxt + kh * 16384, tid);
        stage_unit256(Bn + kh * 32, ldb, nxt + 32768 + kh * 16384, tid);
      }
      asm volatile("s_barrier" ::: "memory");  // phase-lock (reads own data only)
      __builtin_amdgcn_s_setprio(1);
#pragma unroll
      for (int mi = 0; mi < 8; ++mi)
#pragma unroll
        for (int ni = 0; ni < 4; ++ni)
          acc[mi][ni] = __builtin_amdgcn_mfma_f32_16x16x32_bf16(a[mi], b[ni], acc[mi][ni], 0, 0, 0);
      __builtin_amdgcn_s_setprio(0);
      // counted wait: leave this phase's 4 stage-loads in flight; everything
      // older (incl. next phase's khalf, staged 2 phases ago) has landed.
      asm volatile("s_waitcnt vmcnt(4)\n\ts_barrier" ::: "memory");
    }
  }

  // epilogue: C/D layout col=lane&15, row=(lane>>4)*4+reg
#pragma unroll
  for (int mi = 0; mi < 8; ++mi) {
    const int row0 = bx * 256 + wr * 128 + mi * 16 + ((lane >> 4) << 2);
#pragma unroll
    for (int ni = 0; ni < 4; ++ni) {
      const int col = by * 256 + wc * 64 + ni * 16 + (lane & 15);
#pragma unroll
      for (int r = 0; r < 4; ++r) {
        const float v = acc[mi][ni][r] * alpha;
        const long idx = (long)batch * M * N + (long)(row0 + r) * N + col;
        if constexpr (OUT_BF16)
          ((unsigned short*)Call)[idx] = f2bf(v);
        else
          ((float*)Call)[idx] = v;
      }
    }
  }
}

// ---------------- launch ----------------
extern "C" void kernel_launch(void* const* d_in, const int* in_sizes, int n_in,
                              void* d_out, int out_size, void* d_ws, size_t ws_size,
                              hipStream_t stream) {
  const int* x = (const int*)d_in[0];
  const float* emb = (const float*)d_in[1];
  const float* gamma = (const float*)d_in[2];  // [L,E]
  const float* beta = (const float*)d_in[3];   // [L,E]
  const float* Wq = (const float*)d_in[4];     // [L,H,A,E]
  const float* Wk = (const float*)d_in[5];     // [L,H,A,E]
  const float* Wv = (const float*)d_in[6];     // [L,H,E,E]
  float* out = (float*)d_out;                  // [B,H,S,E] f32

  // allow 128 KiB dynamic LDS on the 256^2 kernels (ignore errors: some ROCm
  // versions don't require the opt-in)
  (void)hipFuncSetAttribute(reinterpret_cast<const void*>(&mfma_gemm256_nt<true>),
                            hipFuncAttributeMaxDynamicSharedMemorySize, 131072);
  (void)hipFuncSetAttribute(reinterpret_cast<const void*>(&mfma_gemm256_nt<false>),
                            hipFuncAttributeMaxDynamicSharedMemorySize, 131072);

  // workspace (bf16 shorts): wqk | wv | hn | qk | v_t | sc   (~472 MB)
  const long WQK_N = (long)L_ * H_ * 128 * E_;     // 4M
  const long WV_N = (long)L_ * H_ * E_ * E_;       // 32M
  const long HN_N = (long)B_ * H_ * S_ * E_;       // 64M
  const long QK_N = (long)B_ * H_ * S_ * 128;      // 8M
  unsigned short* wqk = (unsigned short*)d_ws;
  unsigned short* wv_bf = wqk + WQK_N;
  unsigned short* hn = wv_bf + WV_N;               // [B,(H),S,E] bf16
  unsigned short* qk = hn + HN_N;                  // [B,H,S,128] (q | k)
  unsigned short* v_t = qk + QK_N;                 // [B,H,E,S]
  unsigned short* sc = v_t + HN_N;                 // [B,H,S,S]
  unsigned short* hid0 = (unsigned short*)d_out;   // layer-0 hidden, bf16, in d_out

  const dim3 blk(256), blk512(512);
  const dim3 grid256(4, 4, 64);
  cvt_qk_concat<<<2048, blk, 0, stream>>>(Wq, Wk, wqk);
  cvt_f32_bf16<<<4096, blk, 0, stream>>>(Wv, wv_bf, WV_N);

  for (int l = 0; l < L_; ++l) {
    long hSB, hSH;
    if (l == 0) {
      embed_ln_kernel<<<B_ * S_, blk, 0, stream>>>(x, emb, gamma, beta, hn);
      hSB = (long)S_ * E_; hSH = 0;  // heads broadcast at layer 0
    } else {
      ln_bf16_kernel<<<B_ * H_ * S_, blk, 0, stream>>>(
          hid0, gamma + (long)l * E_, beta + (long)l * E_, hn);
      hSB = (long)H_ * S_ * E_; hSH = (long)S_ * E_;
    }
    // qk = hn * [Wq;Wk]^T   [S,128] bf16 (cols 0-63 = q, 64-127 = k)
    mfma_gemm_nt<128, 128, true><<<dim3(8, 1, 64), blk, 0, stream>>>(
        hn, wqk + (long)l * H_ * 128 * E_, qk, S_, 128, E_, E_, E_,
        hSB, hSH, 0L, (long)128 * E_, H_, 1.f);
    // v_t = Wv[l,h] * hn^T  [E,S] bf16
    mfma_gemm256_nt<true><<<grid256, blk512, 131072, stream>>>(
        wv_bf + (long)l * H_ * E_ * E_, hn, v_t, E_, S_, E_, E_, E_,
        0L, (long)E_ * E_, hSB, hSH, H_, 1.f);
    // sc = (q * k^T) / sqrt(E)  [S,S] bf16   (A = qk cols 0-63, B = qk cols 64-127)
    mfma_gemm_nt<128, 128, true><<<dim3(8, 8, 64), blk, 0, stream>>>(
        qk, qk + 64, sc, S_, S_, 64, 128, 128,
        (long)H_ * S_ * 128, (long)S_ * 128, (long)H_ * S_ * 128, (long)S_ * 128, H_, INV_SCALE);
    // softmax rows, in place
    softmax_bf16_kernel<<<B_ * H_ * S_, blk, 0, stream>>>(sc);
    // out = probs * v_t^T  [S,E]; l=0 -> bf16 hidden (in d_out), l=1 -> f32 d_out
    if (l == 0) {
      mfma_gemm256_nt<true><<<grid256, blk512, 131072, stream>>>(
          sc, v_t, hid0, S_, E_, S_, S_, S_,
          (long)H_ * S_ * S_, (long)S_ * S_, (long)H_ * E_ * S_, (long)E_ * S_, H_, 1.f);
    } else {
      mfma_gemm256_nt<false><<<grid256, blk512, 131072, stream>>>(
          sc, v_t, out, S_, E_, S_, S_, S_,
          (long)H_ * S_ * S_, (long)S_ * S_, (long)H_ * E_ * S_, (long)E_ * S_, H_, 1.f);
    }
  }
}

// Round 4
// 975.945 us; speedup vs baseline: 10.4504x; 1.0418x over previous
//
#include <hip/hip_runtime.h>

#define B_ 4
#define S_ 1024
#define E_ 1024
#define A_ 64
#define H_ 16
#define L_ 2

static constexpr float LN_EPS = 1e-5f;
static constexpr float INV_SCALE = 1.0f / 32.0f;  // 1/sqrt(E), E=1024

typedef __attribute__((ext_vector_type(8))) short bf16x8;  // 8 bf16 = 4 VGPRs
typedef __attribute__((ext_vector_type(4))) float f32x4;

// ---------------- bf16 helpers (RNE) ----------------
__device__ __forceinline__ unsigned short f2bf(float f) {
  unsigned u = __float_as_uint(f);
  u += 0x7fffu + ((u >> 16) & 1u);
  return (unsigned short)(u >> 16);
}
__device__ __forceinline__ float bf2f(unsigned short s) {
  return __uint_as_float(((unsigned)s) << 16);
}

// ---------------- block reductions (256 threads = 4 waves) ----------------
__device__ __forceinline__ float block_sum256(float v, float* red) {
#pragma unroll
  for (int o = 32; o > 0; o >>= 1) v += __shfl_down(v, o, 64);
  const int lane = threadIdx.x & 63;
  const int w = threadIdx.x >> 6;
  if (lane == 0) red[w] = v;
  __syncthreads();
  if (threadIdx.x == 0) red[0] = red[0] + red[1] + red[2] + red[3];
  __syncthreads();
  float r = red[0];
  __syncthreads();
  return r;
}

__device__ __forceinline__ float block_max256(float v, float* red) {
#pragma unroll
  for (int o = 32; o > 0; o >>= 1) v = fmaxf(v, __shfl_down(v, o, 64));
  const int lane = threadIdx.x & 63;
  const int w = threadIdx.x >> 6;
  if (lane == 0) red[w] = v;
  __syncthreads();
  if (threadIdx.x == 0) red[0] = fmaxf(fmaxf(red[0], red[1]), fmaxf(red[2], red[3]));
  __syncthreads();
  float r = red[0];
  __syncthreads();
  return r;
}

// ---------------- weight converts ----------------
__global__ __launch_bounds__(256) void cvt_f32_bf16(const float* __restrict__ in,
                                                    unsigned short* __restrict__ out, long n) {
  long i = ((long)blockIdx.x * 256 + threadIdx.x) * 4;
  const long stride = (long)gridDim.x * 1024;
  for (; i < n; i += stride) {
    float4 v = *(const float4*)(in + i);
    ushort4 o;
    o.x = f2bf(v.x); o.y = f2bf(v.y); o.z = f2bf(v.z); o.w = f2bf(v.w);
    *(ushort4*)(out + i) = o;
  }
}

// concat Wq/Wk -> wqk[l,h,128,E] bf16 (rows 0-63 = Wq, 64-127 = Wk)
__global__ __launch_bounds__(256) void cvt_qk_concat(const float* __restrict__ Wq,
                                                     const float* __restrict__ Wk,
                                                     unsigned short* __restrict__ out) {
  const long total = (long)L_ * H_ * 128 * E_;
  long i = ((long)blockIdx.x * 256 + threadIdx.x) * 4;
  const long stride = (long)gridDim.x * 1024;
  for (; i < total; i += stride) {
    const long e = i % E_;
    const long rowhe = i / E_;
    const int row = (int)(rowhe % 128);
    const long lh = rowhe / 128;
    const float* src = (row < 64 ? Wq : Wk) + (lh * 64 + (row & 63)) * E_ + e;
    float4 v = *(const float4*)src;
    ushort4 o;
    o.x = f2bf(v.x); o.y = f2bf(v.y); o.z = f2bf(v.z); o.w = f2bf(v.w);
    *(ushort4*)(out + i) = o;
  }
}

// ---------------- embedding gather + LayerNorm -> bf16 (layer 0) ----------------
__global__ __launch_bounds__(256) void embed_ln_kernel(
    const int* __restrict__ x, const float* __restrict__ emb,
    const float* __restrict__ gamma, const float* __restrict__ beta,
    unsigned short* __restrict__ out) {
  __shared__ float red[4];
  const int row = blockIdx.x;  // b*S + s
  const int tid = threadIdx.x;
  const float* src = emb + (long)x[row] * E_;
  float4 v = *(const float4*)(src + tid * 4);
  const float mean = block_sum256(v.x + v.y + v.z + v.w, red) * (1.f / E_);
  float dx = v.x - mean, dy = v.y - mean, dz = v.z - mean, dw = v.w - mean;
  const float var = block_sum256(dx * dx + dy * dy + dz * dz + dw * dw, red) * (1.f / E_);
  const float rstd = rsqrtf(var + LN_EPS);
  float4 g = *(const float4*)(gamma + tid * 4);
  float4 b = *(const float4*)(beta + tid * 4);
  ushort4 o;
  o.x = f2bf(dx * rstd * g.x + b.x);
  o.y = f2bf(dy * rstd * g.y + b.y);
  o.z = f2bf(dz * rstd * g.z + b.z);
  o.w = f2bf(dw * rstd * g.w + b.w);
  *(ushort4*)(out + (long)row * E_ + tid * 4) = o;
}

// ---------------- LayerNorm bf16 -> bf16 (layer >= 1; hidden lives in d_out as bf16) ----
__global__ __launch_bounds__(256) void ln_bf16_kernel(
    const unsigned short* __restrict__ h, const float* __restrict__ gamma,
    const float* __restrict__ beta, unsigned short* __restrict__ out) {
  __shared__ float red[4];
  const long row = blockIdx.x;  // b*H*S + h*S + s
  const int tid = threadIdx.x;
  ushort4 raw = *(const ushort4*)(h + row * (long)E_ + tid * 4);
  float vx = bf2f(raw.x), vy = bf2f(raw.y), vz = bf2f(raw.z), vw = bf2f(raw.w);
  const float mean = block_sum256(vx + vy + vz + vw, red) * (1.f / E_);
  float dx = vx - mean, dy = vy - mean, dz = vz - mean, dw = vw - mean;
  const float var = block_sum256(dx * dx + dy * dy + dz * dz + dw * dw, red) * (1.f / E_);
  const float rstd = rsqrtf(var + LN_EPS);
  float4 g = *(const float4*)(gamma + tid * 4);
  float4 b = *(const float4*)(beta + tid * 4);
  ushort4 o;
  o.x = f2bf(dx * rstd * g.x + b.x);
  o.y = f2bf(dy * rstd * g.y + b.y);
  o.z = f2bf(dz * rstd * g.z + b.z);
  o.w = f2bf(dw * rstd * g.w + b.w);
  *(ushort4*)(out + row * E_ + tid * 4) = o;
}

// ---------------- softmax over S, bf16 in-place ----------------
__global__ __launch_bounds__(256) void softmax_bf16_kernel(unsigned short* __restrict__ sc) {
  __shared__ float red[4];
  unsigned short* p = sc + (long)blockIdx.x * S_;
  const int tid = threadIdx.x;
  ushort4 raw = *(const ushort4*)(p + tid * 4);
  float v0 = bf2f(raw.x), v1 = bf2f(raw.y), v2 = bf2f(raw.z), v3 = bf2f(raw.w);
  float m = block_max256(fmaxf(fmaxf(v0, v1), fmaxf(v2, v3)), red);
  v0 = __expf(v0 - m); v1 = __expf(v1 - m); v2 = __expf(v2 - m); v3 = __expf(v3 - m);
  const float s = block_sum256(v0 + v1 + v2 + v3, red);
  const float inv = 1.f / s;
  ushort4 o;
  o.x = f2bf(v0 * inv); o.y = f2bf(v1 * inv); o.z = f2bf(v2 * inv); o.w = f2bf(v3 * inv);
  *(ushort4*)(p + tid * 4) = o;
}

// ---------------- global -> LDS direct load (16B/lane) ----------------
__device__ __forceinline__ void gload_lds16(const void* g, void* l) {
  __builtin_amdgcn_global_load_lds((const __attribute__((address_space(1))) void*)g,
                                   (__attribute__((address_space(3))) void*)l, 16, 0, 0);
}

// ============================================================================
// 128x128 2-barrier kernel — used for qk-proj and scores (K=64..1024, small)
// ============================================================================
template <int ROWS>
__device__ __forceinline__ void stage_tile(const unsigned short* __restrict__ src, int ldRow,
                                           unsigned short* lds, int tid) {
  const int rb = tid >> 3;                    // 0..31
  const int gslot = (tid & 7) ^ (rb & 7);     // inverse swizzle on the source
  const int wbase = (tid >> 6) * 512;         // wave-uniform LDS base (shorts)
#pragma unroll
  for (int i = 0; i < ROWS / 32; ++i) {
    const unsigned short* g = src + (long)(i * 32 + rb) * ldRow + gslot * 8;
    gload_lds16(g, lds + i * 2048 + wbase);
  }
}

__device__ __forceinline__ bf16x8 lds_frag(const unsigned short* base, int r, int slot) {
  const int byteoff = (r << 7) + ((slot ^ (r & 7)) << 4);
  return *(const bf16x8*)((const char*)base + byteoff);
}

template <int BM, int BN, bool OUT_BF16>
__global__ __launch_bounds__(256) void mfma_gemm_nt(
    const unsigned short* __restrict__ Aall, const unsigned short* __restrict__ Ball,
    void* __restrict__ Call, int M, int N, int K, int lda, int ldb,
    long aSB, long aSH, long bSB, long bSH, int Hn, float alpha) {
  __shared__ unsigned short As[BM * 64];
  __shared__ unsigned short Bs[BN * 64];
  const int batch = blockIdx.z;
  const int bb = batch / Hn, hh = batch % Hn;
  const unsigned short* Ap = Aall + (long)bb * aSB + (long)hh * aSH;
  const unsigned short* Bp = Ball + (long)bb * bSB + (long)hh * bSH;
  const int tid = threadIdx.x;
  const int lane = tid & 63;
  const int wave = tid >> 6;
  const int wr = wave >> 1, wc = wave & 1;
  const int bm = blockIdx.x * BM, bn = blockIdx.y * BN;
  constexpr int FM = BM / 32, FN = BN / 32;

  f32x4 acc[FM][FN];
#pragma unroll
  for (int i = 0; i < FM; ++i)
#pragma unroll
    for (int j = 0; j < FN; ++j) acc[i][j] = (f32x4)(0.f);

  for (int k0 = 0; k0 < K; k0 += 64) {
    stage_tile<BM>(Ap + (long)bm * lda + k0, lda, As, tid);
    stage_tile<BN>(Bp + (long)bn * ldb + k0, ldb, Bs, tid);
    __syncthreads();
#pragma unroll
    for (int kb = 0; kb < 2; ++kb) {
      const int slot = (kb << 2) + (lane >> 4);
      bf16x8 af[FM], bfv[FN];
#pragma unroll
      for (int mi = 0; mi < FM; ++mi)
        af[mi] = lds_frag(As, wr * (BM / 2) + mi * 16 + (lane & 15), slot);
#pragma unroll
      for (int ni = 0; ni < FN; ++ni)
        bfv[ni] = lds_frag(Bs, wc * (BN / 2) + ni * 16 + (lane & 15), slot);
#pragma unroll
      for (int mi = 0; mi < FM; ++mi)
#pragma unroll
        for (int ni = 0; ni < FN; ++ni)
          acc[mi][ni] = __builtin_amdgcn_mfma_f32_16x16x32_bf16(af[mi], bfv[ni], acc[mi][ni], 0, 0, 0);
    }
    __syncthreads();
  }

#pragma unroll
  for (int mi = 0; mi < FM; ++mi) {
    const int row = bm + wr * (BM / 2) + mi * 16 + ((lane >> 4) << 2);
#pragma unroll
    for (int ni = 0; ni < FN; ++ni) {
      const int col = bn + wc * (BN / 2) + ni * 16 + (lane & 15);
#pragma unroll
      for (int r = 0; r < 4; ++r) {
        const float v = acc[mi][ni][r] * alpha;
        const long idx = (long)batch * M * N + (long)(row + r) * N + col;
        if constexpr (OUT_BF16)
          ((unsigned short*)Call)[idx] = f2bf(v);
        else
          ((float*)Call)[idx] = v;
      }
    }
  }
}

// ============================================================================
// 256x256 8-wave 4-phase-per-K-tile pipelined kernel (m201-style) — v_t and PV
// LDS per buffer (64KB): A [kh][256r][32k] @0, B same @32KB; dbuf at 0/64KB.
// Per K-tile (BK=64), 4 phases:
//   P1: ds_read B(kh0, 4) + A-lo(kh0, 4) | stage A-kh0(t+1) | bar | 16 MFMA | vmcnt(4) bar
//   P2: ds_read A-hi(kh0, 4)             | stage B-kh0(t+1) | bar | 16 MFMA | vmcnt(4) bar
//   P3: ds_read B(kh1, 4) + A-lo(kh1, 4) | stage A-kh1(t+1) | bar | 16 MFMA | vmcnt(4) bar
//   P4: ds_read A-hi(kh1, 4)             | stage B-kh1(t+1) | bar | 16 MFMA | vmcnt(4) bar
// Each half-tile is staged >= 3 phases before consumption; vmcnt(4) at every
// boundary leaves only the last 2 phases' stages outstanding, and since all
// waves issue identical load streams and wait BEFORE the barrier, every half
// older than 2 phases is globally landed. Counted waits, never 0 in the loop.
// ============================================================================
__device__ __forceinline__ void stage_unit256(const unsigned short* __restrict__ src, int ldRow,
                                              char* lds_unit, int tid) {
#pragma unroll
  for (int i = 0; i < 2; ++i) {
    const int r = i * 128 + (tid >> 2);
    const int sg = (tid & 3) ^ ((r >> 1) & 3);  // inverse swizzle on source
    const unsigned short* g = src + (long)r * ldRow + sg * 8;
    gload_lds16(g, lds_unit + i * 8192 + ((tid >> 6) << 10));
  }
}

__device__ __forceinline__ bf16x8 lds_frag256(const char* opbase, int kh, int r, int ss) {
  return *(const bf16x8*)(opbase + kh * 16384 + r * 64 + ((ss ^ ((r >> 1) & 3)) << 4));
}

template <bool OUT_BF16>
__global__ __launch_bounds__(512, 2) void mfma_gemm256_nt(
    const unsigned short* __restrict__ Aall, const unsigned short* __restrict__ Ball,
    void* __restrict__ Call, int M, int N, int K, int lda, int ldb,
    long aSB, long aSH, long bSB, long bSH, int Hn, float alpha) {
  extern __shared__ char lds[];
  // XCD-chunked bijective swizzle on the flat workgroup id (nwg % 8 == 0 here)
  const int nx = gridDim.x, ny = gridDim.y;
  const int nwg = nx * ny * gridDim.z;
  int f = blockIdx.x + nx * (blockIdx.y + ny * blockIdx.z);
  if ((nwg & 7) == 0) f = (f & 7) * (nwg >> 3) + (f >> 3);
  const int bx = f % nx;
  const int by = (f / nx) % ny;
  const int batch = f / (nx * ny);

  const int bb = batch / Hn, hh = batch % Hn;
  const unsigned short* Ap = Aall + (long)bb * aSB + (long)hh * aSH + (long)bx * 256 * lda;
  const unsigned short* Bp = Ball + (long)bb * bSB + (long)hh * bSH + (long)by * 256 * ldb;
  const int tid = threadIdx.x;
  const int lane = tid & 63;
  const int w = tid >> 6;
  const int wr = w >> 2, wc = w & 3;  // 2 (M) x 4 (N) waves; wave tile 128x64
  const int ss = lane >> 4;           // k-slot within kh
  const int ar = lane & 15;           // row within 16

  f32x4 acc[8][4];
#pragma unroll
  for (int i = 0; i < 8; ++i)
#pragma unroll
    for (int j = 0; j < 4; ++j) acc[i][j] = (f32x4)(0.f);

  const int NT = K >> 6;
  // prologue: tile 0 -> buf0, in consumption-order: A-kh0, B-kh0, A-kh1, B-kh1
  stage_unit256(Ap, lda, lds, tid);
  stage_unit256(Bp, ldb, lds + 32768, tid);
  stage_unit256(Ap + 32, lda, lds + 16384, tid);
  stage_unit256(Bp + 32, ldb, lds + 32768 + 16384, tid);
  asm volatile("s_waitcnt vmcnt(4)\n\ts_barrier" ::: "memory");

  for (int t = 0; t < NT; ++t) {
    const char* cur = lds + (t & 1) * 65536;
    char* nxt = lds + ((t + 1) & 1) * 65536;
    const unsigned short* An = Ap + (long)(t + 1) * 64;
    const unsigned short* Bn = Bp + (long)(t + 1) * 64;
    const bool pf = (t + 1 < NT);
    bf16x8 a[4], b[4];

    // ---- P1: kh0, A rows 0-63 of wave tile ----
#pragma unroll
    for (int ni = 0; ni < 4; ++ni)
      b[ni] = lds_frag256(cur + 32768, 0, wc * 64 + ni * 16 + ar, ss);
#pragma unroll
    for (int mi = 0; mi < 4; ++mi)
      a[mi] = lds_frag256(cur, 0, wr * 128 + mi * 16 + ar, ss);
    if (pf) stage_unit256(An, lda, nxt, tid);  // A-kh0'
    asm volatile("s_barrier" ::: "memory");
    __builtin_amdgcn_s_setprio(1);
#pragma unroll
    for (int mi = 0; mi < 4; ++mi)
#pragma unroll
      for (int ni = 0; ni < 4; ++ni)
        acc[mi][ni] = __builtin_amdgcn_mfma_f32_16x16x32_bf16(a[mi], b[ni], acc[mi][ni], 0, 0, 0);
    __builtin_amdgcn_s_setprio(0);
    asm volatile("s_waitcnt vmcnt(4)\n\ts_barrier" ::: "memory");

    // ---- P2: kh0, A rows 64-127 ----
#pragma unroll
    for (int mi = 0; mi < 4; ++mi)
      a[mi] = lds_frag256(cur, 0, wr * 128 + 64 + mi * 16 + ar, ss);
    if (pf) stage_unit256(Bn, ldb, nxt + 32768, tid);  // B-kh0'
    asm volatile("s_barrier" ::: "memory");
    __builtin_amdgcn_s_setprio(1);
#pragma unroll
    for (int mi = 0; mi < 4; ++mi)
#pragma unroll
      for (int ni = 0; ni < 4; ++ni)
        acc[4 + mi][ni] = __builtin_amdgcn_mfma_f32_16x16x32_bf16(a[mi], b[ni], acc[4 + mi][ni], 0, 0, 0);
    __builtin_amdgcn_s_setprio(0);
    asm volatile("s_waitcnt vmcnt(4)\n\ts_barrier" ::: "memory");

    // ---- P3: kh1, A rows 0-63 ----
#pragma unroll
    for (int ni = 0; ni < 4; ++ni)
      b[ni] = lds_frag256(cur + 32768, 1, wc * 64 + ni * 16 + ar, ss);
#pragma unroll
    for (int mi = 0; mi < 4; ++mi)
      a[mi] = lds_frag256(cur, 1, wr * 128 + mi * 16 + ar, ss);
    if (pf) stage_unit256(An + 32, lda, nxt + 16384, tid);  // A-kh1'
    asm volatile("s_barrier" ::: "memory");
    __builtin_amdgcn_s_setprio(1);
#pragma unroll
    for (int mi = 0; mi < 4; ++mi)
#pragma unroll
      for (int ni = 0; ni < 4; ++ni)
        acc[mi][ni] = __builtin_amdgcn_mfma_f32_16x16x32_bf16(a[mi], b[ni], acc[mi][ni], 0, 0, 0);
    __builtin_amdgcn_s_setprio(0);
    asm volatile("s_waitcnt vmcnt(4)\n\ts_barrier" ::: "memory");

    // ---- P4: kh1, A rows 64-127 ----
#pragma unroll
    for (int mi = 0; mi < 4; ++mi)
      a[mi] = lds_frag256(cur, 1, wr * 128 + 64 + mi * 16 + ar, ss);
    if (pf) stage_unit256(Bn + 32, ldb, nxt + 32768 + 16384, tid);  // B-kh1'
    asm volatile("s_barrier" ::: "memory");
    __builtin_amdgcn_s_setprio(1);
#pragma unroll
    for (int mi = 0; mi < 4; ++mi)
#pragma unroll
      for (int ni = 0; ni < 4; ++ni)
        acc[4 + mi][ni] = __builtin_amdgcn_mfma_f32_16x16x32_bf16(a[mi], b[ni], acc[4 + mi][ni], 0, 0, 0);
    __builtin_amdgcn_s_setprio(0);
    asm volatile("s_waitcnt vmcnt(4)\n\ts_barrier" ::: "memory");
  }

  // epilogue: C/D layout col=lane&15, row=(lane>>4)*4+reg
#pragma unroll
  for (int mi = 0; mi < 8; ++mi) {
    const int row0 = bx * 256 + wr * 128 + mi * 16 + ((lane >> 4) << 2);
#pragma unroll
    for (int ni = 0; ni < 4; ++ni) {
      const int col = by * 256 + wc * 64 + ni * 16 + (lane & 15);
#pragma unroll
      for (int r = 0; r < 4; ++r) {
        const float v = acc[mi][ni][r] * alpha;
        const long idx = (long)batch * M * N + (long)(row0 + r) * N + col;
        if constexpr (OUT_BF16)
          ((unsigned short*)Call)[idx] = f2bf(v);
        else
          ((float*)Call)[idx] = v;
      }
    }
  }
}

// ---------------- launch ----------------
extern "C" void kernel_launch(void* const* d_in, const int* in_sizes, int n_in,
                              void* d_out, int out_size, void* d_ws, size_t ws_size,
                              hipStream_t stream) {
  const int* x = (const int*)d_in[0];
  const float* emb = (const float*)d_in[1];
  const float* gamma = (const float*)d_in[2];  // [L,E]
  const float* beta = (const float*)d_in[3];   // [L,E]
  const float* Wq = (const float*)d_in[4];     // [L,H,A,E]
  const float* Wk = (const float*)d_in[5];     // [L,H,A,E]
  const float* Wv = (const float*)d_in[6];     // [L,H,E,E]
  float* out = (float*)d_out;                  // [B,H,S,E] f32

  (void)hipFuncSetAttribute(reinterpret_cast<const void*>(&mfma_gemm256_nt<true>),
                            hipFuncAttributeMaxDynamicSharedMemorySize, 131072);
  (void)hipFuncSetAttribute(reinterpret_cast<const void*>(&mfma_gemm256_nt<false>),
                            hipFuncAttributeMaxDynamicSharedMemorySize, 131072);

  // workspace (bf16 shorts): wqk | wv | hn | qk | v_t | sc   (~472 MB)
  const long WQK_N = (long)L_ * H_ * 128 * E_;     // 4M
  const long WV_N = (long)L_ * H_ * E_ * E_;       // 32M
  const long HN_N = (long)B_ * H_ * S_ * E_;       // 64M
  const long QK_N = (long)B_ * H_ * S_ * 128;      // 8M
  unsigned short* wqk = (unsigned short*)d_ws;
  unsigned short* wv_bf = wqk + WQK_N;
  unsigned short* hn = wv_bf + WV_N;               // [B,(H),S,E] bf16
  unsigned short* qk = hn + HN_N;                  // [B,H,S,128] (q | k)
  unsigned short* v_t = qk + QK_N;                 // [B,H,E,S]
  unsigned short* sc = v_t + HN_N;                 // [B,H,S,S]
  unsigned short* hid0 = (unsigned short*)d_out;   // layer-0 hidden, bf16, in d_out

  const dim3 blk(256), blk512(512);
  const dim3 grid256(4, 4, 64);
  cvt_qk_concat<<<2048, blk, 0, stream>>>(Wq, Wk, wqk);
  cvt_f32_bf16<<<4096, blk, 0, stream>>>(Wv, wv_bf, WV_N);

  for (int l = 0; l < L_; ++l) {
    long hSB, hSH;
    if (l == 0) {
      embed_ln_kernel<<<B_ * S_, blk, 0, stream>>>(x, emb, gamma, beta, hn);
      hSB = (long)S_ * E_; hSH = 0;  // heads broadcast at layer 0
    } else {
      ln_bf16_kernel<<<B_ * H_ * S_, blk, 0, stream>>>(
          hid0, gamma + (long)l * E_, beta + (long)l * E_, hn);
      hSB = (long)H_ * S_ * E_; hSH = (long)S_ * E_;
    }
    // qk = hn * [Wq;Wk]^T   [S,128] bf16 (cols 0-63 = q, 64-127 = k)
    mfma_gemm_nt<128, 128, true><<<dim3(8, 1, 64), blk, 0, stream>>>(
        hn, wqk + (long)l * H_ * 128 * E_, qk, S_, 128, E_, E_, E_,
        hSB, hSH, 0L, (long)128 * E_, H_, 1.f);
    // v_t = Wv[l,h] * hn^T  [E,S] bf16
    mfma_gemm256_nt<true><<<grid256, blk512, 131072, stream>>>(
        wv_bf + (long)l * H_ * E_ * E_, hn, v_t, E_, S_, E_, E_, E_,
        0L, (long)E_ * E_, hSB, hSH, H_, 1.f);
    // sc = (q * k^T) / sqrt(E)  [S,S] bf16   (A = qk cols 0-63, B = qk cols 64-127)
    mfma_gemm_nt<128, 128, true><<<dim3(8, 8, 64), blk, 0, stream>>>(
        qk, qk + 64, sc, S_, S_, 64, 128, 128,
        (long)H_ * S_ * 128, (long)S_ * 128, (long)H_ * S_ * 128, (long)S_ * 128, H_, INV_SCALE);
    // softmax rows, in place
    softmax_bf16_kernel<<<B_ * H_ * S_, blk, 0, stream>>>(sc);
    // out = probs * v_t^T  [S,E]; l=0 -> bf16 hidden (in d_out), l=1 -> f32 d_out
    if (l == 0) {
      mfma_gemm256_nt<true><<<grid256, blk512, 131072, stream>>>(
          sc, v_t, hid0, S_, E_, S_, S_, S_,
          (long)H_ * S_ * S_, (long)S_ * S_, (long)H_ * E_ * S_, (long)E_ * S_, H_, 1.f);
    } else {
      mfma_gemm256_nt<false><<<grid256, blk512, 131072, stream>>>(
          sc, v_t, out, S_, E_, S_, S_, S_,
          (long)H_ * S_ * S_, (long)S_ * S_, (long)H_ * E_ * S_, (long)E_ * S_, H_, 1.f);
    }
  }
}